// Round 4
// baseline (2840.652 us; speedup 1.0000x reference)
//
#include <hip/hip_runtime.h>

typedef unsigned short u16;
typedef unsigned int u32;
typedef __attribute__((ext_vector_type(8))) short bf16x8;
typedef __attribute__((ext_vector_type(8))) unsigned short u16x8;
typedef __attribute__((ext_vector_type(4))) unsigned short u16x4;
typedef __attribute__((ext_vector_type(4))) float f32x4;
typedef __attribute__((ext_vector_type(4))) unsigned int u32x4;

#define S_LEN 2048
#define NB 2
#define NH 32
#define NKVH 8
#define HD 128
#define DMODEL 4096
#define NEG_BIG (-1.0e30f)

__device__ __forceinline__ float bf2f(u16 x) {
  union { u32 u; float f; } v; v.u = ((u32)x) << 16; return v.f;
}
__device__ __forceinline__ u16 f2bf(float f) {
  union { float f; u32 u; } v; v.f = f;
  u32 r = v.u + 0x7FFFu + ((v.u >> 16) & 1u);
  return (u16)(r >> 16);
}

// ---------------------------------------------------------------------------
// GEMM: C[M,N] = A[M,K] @ B[K,N], fp32 accumulate.
// A is fp32 (AF32) or bf16; B is fp32 (weights); C is fp32 (CF32) or bf16.
// 128x128 block tile, BK=32, 256 threads (4 waves, 2x2 grid, 64x64/wave).
// A staged to LDS (m,k) bf16 (+pad); B staged TRANSPOSED to LDS (n,k) bf16.
// ---------------------------------------------------------------------------
template <bool AF32, bool CF32>
__global__ __launch_bounds__(256) void gemm_nn(const void* __restrict__ Av,
                                               const float* __restrict__ B,
                                               void* __restrict__ Cv,
                                               int M, int N, int K)
{
  __shared__ u16 As[128 * 40];
  __shared__ u16 Bs[128 * 40];
  const int tid  = threadIdx.x;
  const int wave = tid >> 6;
  const int lane = tid & 63;
  const int lr   = lane & 15;
  const int quad = lane >> 4;
  const int wm   = (wave >> 1) * 64;
  const int wn   = (wave & 1) * 64;
  const int bm   = blockIdx.y * 128;
  const int bn   = blockIdx.x * 128;

  const f32x4 zero = {0.f, 0.f, 0.f, 0.f};
  f32x4 acc[4][4];
#pragma unroll
  for (int i = 0; i < 4; ++i)
#pragma unroll
    for (int j = 0; j < 4; ++j) acc[i][j] = zero;

  for (int kt = 0; kt < K; kt += 32) {
    __syncthreads();
    // ---- stage A tile (128 x 32) as bf16 ----
    if (AF32) {
      const float* A = (const float*)Av;
#pragma unroll
      for (int i = 0; i < 4; ++i) {
        int e = (tid + i * 256) * 4;           // 4 elems/thread/iter
        int row = e >> 5, col = e & 31;
        f32x4 v = *(const f32x4*)&A[(size_t)(bm + row) * K + kt + col];
        u16x4 h = { f2bf(v[0]), f2bf(v[1]), f2bf(v[2]), f2bf(v[3]) };
        *(u16x4*)&As[row * 40 + col] = h;      // 8B store, aligned (col%4==0)
      }
    } else {
      const u16* A = (const u16*)Av;
#pragma unroll
      for (int i = 0; i < 2; ++i) {
        int e = (tid + i * 256) * 8;           // 8 elems/thread/iter
        int row = e >> 5, col = e & 31;
        u32x4 v = *(const u32x4*)&A[(size_t)(bm + row) * K + kt + col];
        *(u32x4*)&As[row * 40 + col] = v;
      }
    }
    // ---- stage B tile (32 x 128) fp32 -> bf16 transposed into Bs[n][k] ----
#pragma unroll
    for (int i = 0; i < 4; ++i) {
      int e = (tid + i * 256) * 4;
      int krow = e >> 7, ncol = e & 127;
      f32x4 v = *(const f32x4*)&B[(size_t)(kt + krow) * N + bn + ncol];
#pragma unroll
      for (int j = 0; j < 4; ++j) Bs[(ncol + j) * 40 + krow] = f2bf(v[j]);
    }
    __syncthreads();

    bf16x8 af[4], bfr[4];
#pragma unroll
    for (int mt = 0; mt < 4; ++mt)
      af[mt] = *(const bf16x8*)&As[(wm + mt * 16 + lr) * 40 + quad * 8];
#pragma unroll
    for (int nt = 0; nt < 4; ++nt)
      bfr[nt] = *(const bf16x8*)&Bs[(wn + nt * 16 + lr) * 40 + quad * 8];
#pragma unroll
    for (int mt = 0; mt < 4; ++mt)
#pragma unroll
      for (int nt = 0; nt < 4; ++nt)
        acc[mt][nt] = __builtin_amdgcn_mfma_f32_16x16x32_bf16(af[mt], bfr[nt], acc[mt][nt], 0, 0, 0);
  }

#pragma unroll
  for (int mt = 0; mt < 4; ++mt)
#pragma unroll
    for (int nt = 0; nt < 4; ++nt)
#pragma unroll
      for (int r = 0; r < 4; ++r) {
        size_t m = (size_t)(bm + wm + mt * 16 + quad * 4 + r);
        size_t n = (size_t)(bn + wn + nt * 16 + lr);
        if (CF32) ((float*)Cv)[m * N + n] = acc[mt][nt][r];
        else      ((u16*)Cv)[m * N + n]   = f2bf(acc[mt][nt][r]);
      }
}

// ---------------------------------------------------------------------------
// RoPE in-place on Y[(b,s,nh,HD)] bf16 workspace; freqs are fp32 inputs.
// idx = ((b*S+s)*nh + h)*64 + j
// ---------------------------------------------------------------------------
__global__ __launch_bounds__(256) void rope_kernel(u16* __restrict__ Y,
                                                   const float* __restrict__ cp,
                                                   const float* __restrict__ sp,
                                                   int log2nh, int total)
{
  int idx = blockIdx.x * 256 + threadIdx.x;
  if (idx >= total) return;
  int j = idx & 63;
  int s = (idx >> (6 + log2nh)) & (S_LEN - 1);
  u16 t0 = Y[(size_t)idx * 2];
  u16 t1 = Y[(size_t)idx * 2 + 1];
  float tr = bf2f(t0), ti = bf2f(t1);
  float c  = cp[s * 64 + j];
  float sn = sp[s * 64 + j];
  Y[(size_t)idx * 2]     = f2bf(tr * c - ti * sn);
  Y[(size_t)idx * 2 + 1] = f2bf(tr * sn + ti * c);
}

// ---------------------------------------------------------------------------
// Flash attention, causal, GQA (REP=4). Block = 64 q-rows of one (b,h).
// 4 waves x 16 q-rows. KV tile = 32. Online softmax, no infinities.
// Q,K,V: bf16 workspace. O (bf16) may alias Q: each block reads only its own
// (b,q-range,h) slice at start and writes the same slice at the end.
// ---------------------------------------------------------------------------
__global__ __launch_bounds__(256) void attn_kernel(const u16* Q,
                                                   const u16* __restrict__ K,
                                                   const u16* __restrict__ V,
                                                   u16* O)
{
  __shared__ u16 Ks[32 * 136];    // (kv, d) pad to 136
  __shared__ u16 Vs[128 * 40];    // transposed: (d, kv) pad to 40
  __shared__ u16 Ps[4 * 16 * 40]; // per-wave P tile (q, kv) pad to 40

  const int tid  = threadIdx.x;
  const int wave = tid >> 6;
  const int lane = tid & 63;
  const int lr   = lane & 15;
  const int quad = lane >> 4;

  const int b   = blockIdx.z;
  const int h   = blockIdx.y;
  const int q0  = blockIdx.x * 64;
  const int kvh = h >> 2;   // REP = 4

  const int qrow = q0 + wave * 16 + lr;
  const u16* qptr = Q + ((size_t)((b * S_LEN + qrow) * NH + h)) * HD;
  bf16x8 aq[4];
#pragma unroll
  for (int c = 0; c < 4; ++c) aq[c] = *(const bf16x8*)(qptr + c * 32 + quad * 8);

  const f32x4 zero = {0.f, 0.f, 0.f, 0.f};
  f32x4 accO[8];
#pragma unroll
  for (int nt = 0; nt < 8; ++nt) accO[nt] = zero;
  float m_run[4], l_run[4];
#pragma unroll
  for (int r = 0; r < 4; ++r) { m_run[r] = NEG_BIG; l_run[r] = 0.f; }

  const float scale = 0.08838834764831845f;  // 1/sqrt(128)
  const int myq = q0 + wave * 16 + quad * 4;

  for (int kv0 = 0; kv0 < q0 + 64; kv0 += 32) {
    __syncthreads();
#pragma unroll
    for (int i = 0; i < 2; ++i) {
      int e = (tid + i * 256) * 8;
      int krow = e >> 7, d = e & 127;
      size_t base = ((size_t)((b * S_LEN + kv0 + krow) * NKVH + kvh)) * HD + d;
      u32x4 kv = *(const u32x4*)&K[base];
      *(u32x4*)&Ks[krow * 136 + d] = kv;
      u16x8 vv = *(const u16x8*)&V[base];
#pragma unroll
      for (int j = 0; j < 8; ++j) Vs[(d + j) * 40 + krow] = vv[j];
    }
    __syncthreads();

    f32x4 acc0 = zero, acc1 = zero;
#pragma unroll
    for (int c = 0; c < 4; ++c) {
      bf16x8 bk = *(const bf16x8*)&Ks[lr * 136 + c * 32 + quad * 8];
      acc0 = __builtin_amdgcn_mfma_f32_16x16x32_bf16(aq[c], bk, acc0, 0, 0, 0);
    }
#pragma unroll
    for (int c = 0; c < 4; ++c) {
      bf16x8 bk = *(const bf16x8*)&Ks[(16 + lr) * 136 + c * 32 + quad * 8];
      acc1 = __builtin_amdgcn_mfma_f32_16x16x32_bf16(aq[c], bk, acc1, 0, 0, 0);
    }

    float alpha[4];
#pragma unroll
    for (int r = 0; r < 4; ++r) {
      float s0 = (kv0 + lr      <= myq + r) ? acc0[r] * scale : NEG_BIG;
      float s1 = (kv0 + 16 + lr <= myq + r) ? acc1[r] * scale : NEG_BIG;
      float mx = fmaxf(s0, s1);
#pragma unroll
      for (int off = 8; off >= 1; off >>= 1) mx = fmaxf(mx, __shfl_xor(mx, off));
      float mn = fmaxf(m_run[r], mx);
      alpha[r] = __expf(m_run[r] - mn);
      m_run[r] = mn;
      float p0 = __expf(s0 - mn);   // masked: exp(~-1e30) -> 0
      float p1 = __expf(s1 - mn);
      float rs = p0 + p1;
#pragma unroll
      for (int off = 8; off >= 1; off >>= 1) rs += __shfl_xor(rs, off);
      l_run[r] = l_run[r] * alpha[r] + rs;
      Ps[wave * 640 + (quad * 4 + r) * 40 + lr]      = f2bf(p0);
      Ps[wave * 640 + (quad * 4 + r) * 40 + 16 + lr] = f2bf(p1);
    }
#pragma unroll
    for (int nt = 0; nt < 8; ++nt)
#pragma unroll
      for (int r = 0; r < 4; ++r) accO[nt][r] *= alpha[r];

    bf16x8 pf = *(const bf16x8*)&Ps[wave * 640 + lr * 40 + quad * 8];
#pragma unroll
    for (int nt = 0; nt < 8; ++nt) {
      bf16x8 vf = *(const bf16x8*)&Vs[(nt * 16 + lr) * 40 + quad * 8];
      accO[nt] = __builtin_amdgcn_mfma_f32_16x16x32_bf16(pf, vf, accO[nt], 0, 0, 0);
    }
  }

  float rl[4];
#pragma unroll
  for (int r = 0; r < 4; ++r) rl[r] = 1.0f / l_run[r];
#pragma unroll
  for (int nt = 0; nt < 8; ++nt)
#pragma unroll
    for (int r = 0; r < 4; ++r) {
      size_t q = (size_t)(q0 + wave * 16 + quad * 4 + r);
      O[((size_t)b * S_LEN + q) * DMODEL + (size_t)h * HD + nt * 16 + lr] =
          f2bf(accO[nt][r] * rl[r]);
    }
}

extern "C" void kernel_launch(void* const* d_in, const int* in_sizes, int n_in,
                              void* d_out, int out_size, void* d_ws, size_t ws_size,
                              hipStream_t stream)
{
  // Inputs fp32 per the reference's setup_inputs dtypes; output fp32 likewise.
  const float* x  = (const float*)d_in[0];
  const float* cp = (const float*)d_in[1];
  const float* sp = (const float*)d_in[2];
  const float* Wq = (const float*)d_in[3];
  const float* Wk = (const float*)d_in[4];
  const float* Wv = (const float*)d_in[5];
  const float* Wo = (const float*)d_in[6];

  u16* Yq  = (u16*)d_ws;                 // 16,777,216 elems (b,s,H,HD) bf16
  u16* Yk  = Yq + (size_t)16777216;      //  4,194,304 elems (b,s,KVH,HD)
  u16* Yv  = Yk + (size_t)4194304;       //  4,194,304 elems (b,s,KVH,HD)
  u16* att = Yq;                         // attn output aliases Q (disjoint
                                         // per-block read-then-write)

  const int M = NB * S_LEN;  // 4096

  gemm_nn<true, false><<<dim3(32, 32), 256, 0, stream>>>((const void*)x, Wq, Yq, M, 4096, 4096);
  gemm_nn<true, false><<<dim3(8, 32),  256, 0, stream>>>((const void*)x, Wk, Yk, M, 1024, 4096);
  gemm_nn<true, false><<<dim3(8, 32),  256, 0, stream>>>((const void*)x, Wv, Yv, M, 1024, 4096);
  rope_kernel<<<32768, 256, 0, stream>>>(Yq, cp, sp, 5, 8388608);
  rope_kernel<<<8192, 256, 0, stream>>>(Yk, cp, sp, 3, 2097152);
  attn_kernel<<<dim3(32, 32, 2), 256, 0, stream>>>(Yq, Yk, Yv, att);
  gemm_nn<false, true><<<dim3(32, 32), 256, 0, stream>>>((const void*)att, Wo, d_out, M, 4096, 4096);
}

// Round 5
// 1152.636 us; speedup vs baseline: 2.4645x; 2.4645x over previous
//
#include <hip/hip_runtime.h>

typedef unsigned short u16;
typedef unsigned int u32;
typedef __attribute__((ext_vector_type(8))) short bf16x8;
typedef __attribute__((ext_vector_type(8))) unsigned short u16x8;
typedef __attribute__((ext_vector_type(4))) unsigned short u16x4;
typedef __attribute__((ext_vector_type(4))) float f32x4;
typedef __attribute__((ext_vector_type(4))) unsigned int u32x4;

#define S_LEN 2048
#define NB 2
#define NH 32
#define NKVH 8
#define HD 128
#define DMODEL 4096
#define NEG_BIG (-1.0e30f)

__device__ __forceinline__ float bf2f(u16 x) {
  union { u32 u; float f; } v; v.u = ((u32)x) << 16; return v.f;
}
__device__ __forceinline__ u16 f2bf(float f) {
  union { float f; u32 u; } v; v.f = f;
  u32 r = v.u + 0x7FFFu + ((v.u >> 16) & 1u);
  return (u16)(r >> 16);
}

// ---------------------------------------------------------------------------
// Transpose+convert: W fp32 (4096=K rows, N cols) -> out bf16 (N rows, 4096).
// 64x64 tiles via LDS. Caller applies output row offset via `out` pointer.
// ---------------------------------------------------------------------------
__global__ __launch_bounds__(256) void transpose_w(const float* __restrict__ W,
                                                   u16* __restrict__ out,
                                                   int N)
{
  __shared__ u16 Ls[64 * 68];
  const int t  = threadIdx.x;
  const int k0 = blockIdx.x * 64;
  const int n0 = blockIdx.y * 64;
#pragma unroll
  for (int i = 0; i < 4; ++i) {
    int kr = (t >> 4) + i * 16;
    int nc = (t & 15) * 4;
    f32x4 v = *(const f32x4*)&W[(size_t)(k0 + kr) * N + n0 + nc];
    u16x4 h = { f2bf(v[0]), f2bf(v[1]), f2bf(v[2]), f2bf(v[3]) };
    *(u16x4*)&Ls[kr * 68 + nc] = h;
  }
  __syncthreads();
#pragma unroll
  for (int i = 0; i < 2; ++i) {
    int nr = (t >> 3) + i * 32;
    int kc = (t & 7) * 8;
    u16x8 h;
#pragma unroll
    for (int j = 0; j < 8; ++j) h[j] = Ls[(kc + j) * 68 + nr];
    *(u16x8*)&out[(size_t)(n0 + nr) * 4096 + k0 + kc] = h;
  }
}

// ---------------------------------------------------------------------------
// QKV GEMM: A = x fp32 (4096, 4096); Bt = Wt bf16 (6144 n-rows, 4096 k).
// C routed per-block: n<4096 -> Yq, <5120 -> Yk, else Yv (bf16).
// 128x128 tile, BK=32, 4 waves. A fp32->bf16 convert at staging; B vector copy.
// ---------------------------------------------------------------------------
__global__ __launch_bounds__(256) void gemm_qkv(const float* __restrict__ A,
                                                const u16* __restrict__ Bt,
                                                u16* __restrict__ Yq,
                                                u16* __restrict__ Yk,
                                                u16* __restrict__ Yv)
{
  __shared__ u16 As[128 * 40];
  __shared__ u16 Bs[128 * 40];
  const int tid  = threadIdx.x;
  const int wave = tid >> 6;
  const int lane = tid & 63;
  const int lr   = lane & 15;
  const int quad = lane >> 4;
  const int wm   = (wave >> 1) * 64;
  const int wn   = (wave & 1) * 64;
  const int bm   = blockIdx.y * 128;
  const int bn   = blockIdx.x * 128;

  const f32x4 zero = {0.f, 0.f, 0.f, 0.f};
  f32x4 acc[4][4];
#pragma unroll
  for (int i = 0; i < 4; ++i)
#pragma unroll
    for (int j = 0; j < 4; ++j) acc[i][j] = zero;

  for (int kt = 0; kt < 4096; kt += 32) {
    __syncthreads();
#pragma unroll
    for (int i = 0; i < 4; ++i) {                 // A: fp32 -> bf16
      int e = (tid + i * 256) * 4;
      int row = e >> 5, col = e & 31;
      f32x4 v = *(const f32x4*)&A[(size_t)(bm + row) * 4096 + kt + col];
      u16x4 h = { f2bf(v[0]), f2bf(v[1]), f2bf(v[2]), f2bf(v[3]) };
      *(u16x4*)&As[row * 40 + col] = h;
    }
#pragma unroll
    for (int i = 0; i < 2; ++i) {                 // B: bf16 vector copy
      int e = (tid + i * 256) * 8;
      int nr = e >> 5, kc = e & 31;
      *(u32x4*)&Bs[nr * 40 + kc] =
          *(const u32x4*)&Bt[(size_t)(bn + nr) * 4096 + kt + kc];
    }
    __syncthreads();

    bf16x8 af[4], bfr[4];
#pragma unroll
    for (int mt = 0; mt < 4; ++mt)
      af[mt] = *(const bf16x8*)&As[(wm + mt * 16 + lr) * 40 + quad * 8];
#pragma unroll
    for (int nt = 0; nt < 4; ++nt)
      bfr[nt] = *(const bf16x8*)&Bs[(wn + nt * 16 + lr) * 40 + quad * 8];
#pragma unroll
    for (int mt = 0; mt < 4; ++mt)
#pragma unroll
      for (int nt = 0; nt < 4; ++nt)
        acc[mt][nt] = __builtin_amdgcn_mfma_f32_16x16x32_bf16(af[mt], bfr[nt], acc[mt][nt], 0, 0, 0);
  }

  u16* dst; size_t ldc; int nbase;
  if (bn < 4096)      { dst = Yq; ldc = 4096; nbase = bn; }
  else if (bn < 5120) { dst = Yk; ldc = 1024; nbase = bn - 4096; }
  else                { dst = Yv; ldc = 1024; nbase = bn - 5120; }
#pragma unroll
  for (int mt = 0; mt < 4; ++mt)
#pragma unroll
    for (int nt = 0; nt < 4; ++nt)
#pragma unroll
      for (int r = 0; r < 4; ++r) {
        size_t m = (size_t)(bm + wm + mt * 16 + quad * 4 + r);
        size_t n = (size_t)(nbase + wn + nt * 16 + lr);
        dst[m * ldc + n] = f2bf(acc[mt][nt][r]);
      }
}

// ---------------------------------------------------------------------------
// O GEMM: A = att bf16 (4096, 4096); Bt = WoT bf16 (4096, 4096); C fp32 out.
// ---------------------------------------------------------------------------
__global__ __launch_bounds__(256) void gemm_o(const u16* __restrict__ A,
                                              const u16* __restrict__ Bt,
                                              float* __restrict__ C)
{
  __shared__ u16 As[128 * 40];
  __shared__ u16 Bs[128 * 40];
  const int tid  = threadIdx.x;
  const int wave = tid >> 6;
  const int lane = tid & 63;
  const int lr   = lane & 15;
  const int quad = lane >> 4;
  const int wm   = (wave >> 1) * 64;
  const int wn   = (wave & 1) * 64;
  const int bm   = blockIdx.y * 128;
  const int bn   = blockIdx.x * 128;

  const f32x4 zero = {0.f, 0.f, 0.f, 0.f};
  f32x4 acc[4][4];
#pragma unroll
  for (int i = 0; i < 4; ++i)
#pragma unroll
    for (int j = 0; j < 4; ++j) acc[i][j] = zero;

  for (int kt = 0; kt < 4096; kt += 32) {
    __syncthreads();
#pragma unroll
    for (int i = 0; i < 2; ++i) {
      int e = (tid + i * 256) * 8;
      int row = e >> 5, col = e & 31;
      *(u32x4*)&As[row * 40 + col] =
          *(const u32x4*)&A[(size_t)(bm + row) * 4096 + kt + col];
    }
#pragma unroll
    for (int i = 0; i < 2; ++i) {
      int e = (tid + i * 256) * 8;
      int nr = e >> 5, kc = e & 31;
      *(u32x4*)&Bs[nr * 40 + kc] =
          *(const u32x4*)&Bt[(size_t)(bn + nr) * 4096 + kt + kc];
    }
    __syncthreads();

    bf16x8 af[4], bfr[4];
#pragma unroll
    for (int mt = 0; mt < 4; ++mt)
      af[mt] = *(const bf16x8*)&As[(wm + mt * 16 + lr) * 40 + quad * 8];
#pragma unroll
    for (int nt = 0; nt < 4; ++nt)
      bfr[nt] = *(const bf16x8*)&Bs[(wn + nt * 16 + lr) * 40 + quad * 8];
#pragma unroll
    for (int mt = 0; mt < 4; ++mt)
#pragma unroll
      for (int nt = 0; nt < 4; ++nt)
        acc[mt][nt] = __builtin_amdgcn_mfma_f32_16x16x32_bf16(af[mt], bfr[nt], acc[mt][nt], 0, 0, 0);
  }

#pragma unroll
  for (int mt = 0; mt < 4; ++mt)
#pragma unroll
    for (int nt = 0; nt < 4; ++nt)
#pragma unroll
      for (int r = 0; r < 4; ++r) {
        size_t m = (size_t)(bm + wm + mt * 16 + quad * 4 + r);
        size_t n = (size_t)(bn + wn + nt * 16 + lr);
        C[m * 4096 + n] = acc[mt][nt][r];
      }
}

// ---------------------------------------------------------------------------
// RoPE in-place on Y[(b,s,nh,HD)] bf16 workspace; freqs fp32.
// ---------------------------------------------------------------------------
__global__ __launch_bounds__(256) void rope_kernel(u16* __restrict__ Y,
                                                   const float* __restrict__ cp,
                                                   const float* __restrict__ sp,
                                                   int log2nh, int total)
{
  int idx = blockIdx.x * 256 + threadIdx.x;
  if (idx >= total) return;
  int j = idx & 63;
  int s = (idx >> (6 + log2nh)) & (S_LEN - 1);
  u16 t0 = Y[(size_t)idx * 2];
  u16 t1 = Y[(size_t)idx * 2 + 1];
  float tr = bf2f(t0), ti = bf2f(t1);
  float c  = cp[s * 64 + j];
  float sn = sp[s * 64 + j];
  Y[(size_t)idx * 2]     = f2bf(tr * c - ti * sn);
  Y[(size_t)idx * 2 + 1] = f2bf(tr * sn + ti * c);
}

// ---------------------------------------------------------------------------
// Flash attention, causal, GQA (REP=4). Block = 64 q-rows of one (b,h).
// 4 waves x 16 q-rows. KV tile = 64. Online softmax (no infinities).
// Vs transposed (d, kv) with XOR swizzle kv^=((d>>3)&7)<<3 (kills the 32-way
// write conflict, keeps 8-elem runs for ds_read_b128). Ps swizzled likewise
// by q-row. Only the diagonal KV tile applies the causal mask (uniform branch).
// Heavy blocks (large q0) launch first via reversed blockIdx.x.
// O aliases Q (per-block disjoint read-then-write).
// ---------------------------------------------------------------------------
__global__ __launch_bounds__(256) void attn_kernel(const u16* Q,
                                                   const u16* __restrict__ K,
                                                   const u16* __restrict__ V,
                                                   u16* O)
{
  __shared__ u16 Ks[64 * 136];     // (kv, d)
  __shared__ u16 Vs[128 * 72];     // (d, kv^swz)
  __shared__ u16 Ps[4 * 16 * 72];  // per-wave (q, kv^swz)

  const int tid  = threadIdx.x;
  const int wave = tid >> 6;
  const int lane = tid & 63;
  const int lr   = lane & 15;
  const int quad = lane >> 4;

  const int b   = blockIdx.z;
  const int h   = blockIdx.y;
  const int q0  = ((int)gridDim.x - 1 - (int)blockIdx.x) * 64;  // heavy first
  const int kvh = h >> 2;   // REP = 4

  const int qrow = q0 + wave * 16 + lr;
  const u16* qptr = Q + ((size_t)((b * S_LEN + qrow) * NH + h)) * HD;
  bf16x8 aq[4];
#pragma unroll
  for (int c = 0; c < 4; ++c) aq[c] = *(const bf16x8*)(qptr + c * 32 + quad * 8);

  const f32x4 zero = {0.f, 0.f, 0.f, 0.f};
  f32x4 accO[8];
#pragma unroll
  for (int nt = 0; nt < 8; ++nt) accO[nt] = zero;
  float m_run[4], l_run[4];
#pragma unroll
  for (int r = 0; r < 4; ++r) { m_run[r] = NEG_BIG; l_run[r] = 0.f; }

  const float scale = 0.08838834764831845f;  // 1/sqrt(128)
  const int myq = q0 + wave * 16 + quad * 4;

  for (int kv0 = 0; kv0 <= q0; kv0 += 64) {
    const bool diag = (kv0 == q0);
    __syncthreads();
    // stage K (kv,d) vector; V transposed+swizzled
#pragma unroll
    for (int i = 0; i < 4; ++i) {
      int e = (tid + i * 256) * 8;
      int krow = e >> 7, d0 = e & 127;
      size_t base = ((size_t)((b * S_LEN + kv0 + krow) * NKVH + kvh)) * HD + d0;
      *(u32x4*)&Ks[krow * 136 + d0] = *(const u32x4*)&K[base];
      u16x8 vv = *(const u16x8*)&V[base];
      int kr2 = krow ^ (((d0 >> 3) & 7) << 3);
#pragma unroll
      for (int j = 0; j < 8; ++j) Vs[(d0 + j) * 72 + kr2] = vv[j];
    }
    __syncthreads();

    // S = Q K^T : 16 q x 64 kv per wave (4 col-tiles)
    f32x4 sa[4];
#pragma unroll
    for (int t = 0; t < 4; ++t) {
      f32x4 a = zero;
#pragma unroll
      for (int c = 0; c < 4; ++c) {
        bf16x8 bk = *(const bf16x8*)&Ks[(t * 16 + lr) * 136 + c * 32 + quad * 8];
        a = __builtin_amdgcn_mfma_f32_16x16x32_bf16(aq[c], bk, a, 0, 0, 0);
      }
      sa[t] = a;
    }

    // online softmax per row (rows = myq + r)
    float alpha[4];
#pragma unroll
    for (int r = 0; r < 4; ++r) {
      const int row = myq + r;
      float s[4];
#pragma unroll
      for (int t = 0; t < 4; ++t) {
        float v = sa[t][r] * scale;
        if (diag) v = (kv0 + t * 16 + lr <= row) ? v : NEG_BIG;
        s[t] = v;
      }
      float mx = fmaxf(fmaxf(s[0], s[1]), fmaxf(s[2], s[3]));
#pragma unroll
      for (int off = 8; off >= 1; off >>= 1) mx = fmaxf(mx, __shfl_xor(mx, off));
      float mn = fmaxf(m_run[r], mx);
      alpha[r] = __expf(m_run[r] - mn);
      m_run[r] = mn;
      float p[4], rs = 0.f;
#pragma unroll
      for (int t = 0; t < 4; ++t) { p[t] = __expf(s[t] - mn); rs += p[t]; }
#pragma unroll
      for (int off = 8; off >= 1; off >>= 1) rs += __shfl_xor(rs, off);
      l_run[r] = l_run[r] * alpha[r] + rs;
      const int q  = quad * 4 + r;
      const int sw = (q & 7) << 3;
      const int base = wave * 1152 + q * 72;
#pragma unroll
      for (int t = 0; t < 4; ++t) Ps[base + ((t * 16 + lr) ^ sw)] = f2bf(p[t]);
    }
#pragma unroll
    for (int nt = 0; nt < 8; ++nt)
#pragma unroll
      for (int r = 0; r < 4; ++r) accO[nt][r] *= alpha[r];

    // O += P V : 2 k-steps of 32 kv, 8 d-tiles
#pragma unroll
    for (int kt2 = 0; kt2 < 2; ++kt2) {
      bf16x8 pf = *(const bf16x8*)&Ps[wave * 1152 + lr * 72 +
                                      ((kt2 * 32 + quad * 8) ^ ((lr & 7) << 3))];
#pragma unroll
      for (int nt = 0; nt < 8; ++nt) {
        const int d = nt * 16 + lr;
        bf16x8 vf = *(const bf16x8*)&Vs[d * 72 +
                                        ((kt2 * 32 + quad * 8) ^ (((d >> 3) & 7) << 3))];
        accO[nt] = __builtin_amdgcn_mfma_f32_16x16x32_bf16(pf, vf, accO[nt], 0, 0, 0);
      }
    }
  }

  float rl[4];
#pragma unroll
  for (int r = 0; r < 4; ++r) rl[r] = 1.0f / l_run[r];
#pragma unroll
  for (int nt = 0; nt < 8; ++nt)
#pragma unroll
    for (int r = 0; r < 4; ++r) {
      size_t q = (size_t)(q0 + wave * 16 + quad * 4 + r);
      O[((size_t)b * S_LEN + q) * DMODEL + (size_t)h * HD + nt * 16 + lr] =
          f2bf(accO[nt][r] * rl[r]);
    }
}

extern "C" void kernel_launch(void* const* d_in, const int* in_sizes, int n_in,
                              void* d_out, int out_size, void* d_ws, size_t ws_size,
                              hipStream_t stream)
{
  const float* x  = (const float*)d_in[0];
  const float* cp = (const float*)d_in[1];
  const float* sp = (const float*)d_in[2];
  const float* Wq = (const float*)d_in[3];
  const float* Wk = (const float*)d_in[4];
  const float* Wv = (const float*)d_in[5];
  const float* Wo = (const float*)d_in[6];

  // ws layout (bf16 elems): Wt 25,165,824 | Yq 16,777,216 | Yk 4,194,304 |
  // Yv 4,194,304  (peak 96 MB). WoT reuses the Wt region after attention.
  u16* Wt  = (u16*)d_ws;
  u16* Yq  = Wt + (size_t)25165824;
  u16* Yk  = Yq + (size_t)16777216;
  u16* Yv  = Yk + (size_t)4194304;
  u16* att = Yq;                       // attn output aliases Q
  u16* WoT = Wt;                       // dead after QKV GEMM

  transpose_w<<<dim3(64, 64), 256, 0, stream>>>(Wq, Wt,                    4096);
  transpose_w<<<dim3(64, 16), 256, 0, stream>>>(Wk, Wt + (size_t)4096*4096, 1024);
  transpose_w<<<dim3(64, 16), 256, 0, stream>>>(Wv, Wt + (size_t)5120*4096, 1024);
  gemm_qkv<<<dim3(48, 32), 256, 0, stream>>>(x, Wt, Yq, Yk, Yv);
  rope_kernel<<<32768, 256, 0, stream>>>(Yq, cp, sp, 5, 8388608);
  rope_kernel<<<8192, 256, 0, stream>>>(Yk, cp, sp, 3, 2097152);
  attn_kernel<<<dim3(32, 32, 2), 256, 0, stream>>>(Yq, Yk, Yv, att);
  transpose_w<<<dim3(64, 64), 256, 0, stream>>>(Wo, WoT, 4096);
  gemm_o<<<dim3(32, 32), 256, 0, stream>>>(att, WoT, (float*)d_out);
}